// Round 5
// baseline (544.306 us; speedup 1.0000x reference)
//
#include <hip/hip_runtime.h>

// GCN: 2x GCNConv(128->128) + mean-pool + MLP(128->128->2), fp32.
// R4: k_gemm v3 — NO LDS. W read from global (L2-hot, 4 lines/instr via
// og-sharing); 64 nodes x 128 outs per block; 16og x 16ng layout maximizes
// per-line lane sharing (dup4 on X, dup16 on W); X next-k prefetch into regs;
// no LDS -> 16 waves/CU at launch_bounds(256,4). Rest unchanged from R3.

__global__ void k_init(float* deg, int* counts, int* cursor, int N,
                       float* pooled, int M) {
    int i = blockIdx.x * blockDim.x + threadIdx.x;
    if (i < N) { deg[i] = 1.0f; counts[i] = 0; cursor[i] = 0; }  // self-loop weight 1
    if (i < M) pooled[i] = 0.f;
}

__global__ void k_deg_hist(const int* __restrict__ col, const float* __restrict__ ew,
                           float* deg, int* counts, int E) {
    int e = blockIdx.x * blockDim.x + threadIdx.x;
    if (e < E) {
        int c = col[e];
        atomicAdd(&deg[c], ew[e]);
        atomicAdd(&counts[c], 1);
    }
}

__global__ void k_dinv(const float* __restrict__ deg, float* dinv, int N) {
    int i = blockIdx.x * blockDim.x + threadIdx.x;
    if (i < N) { float d = deg[i]; dinv[i] = d > 0.f ? rsqrtf(d) : 0.f; }
}

// --- 3-kernel exclusive scan over counts[N] -> offs[N+1] ---
__global__ void k_scan1(const int* __restrict__ counts, int* __restrict__ offs,
                        int* __restrict__ bsums, int N) {
    __shared__ int lds[256];
    int t = threadIdx.x;
    int base = blockIdx.x * 1024 + t * 4;
    int a0 = 0, a1 = 0, a2 = 0, a3 = 0;
    if (base + 3 < N) {
        int4 v = *(const int4*)(counts + base);
        a0 = v.x; a1 = v.y; a2 = v.z; a3 = v.w;
    } else {
        if (base + 0 < N) a0 = counts[base + 0];
        if (base + 1 < N) a1 = counts[base + 1];
        if (base + 2 < N) a2 = counts[base + 2];
        if (base + 3 < N) a3 = counts[base + 3];
    }
    int tsum = a0 + a1 + a2 + a3;
    lds[t] = tsum;
    __syncthreads();
    for (int d = 1; d < 256; d <<= 1) {
        int v = (t >= d) ? lds[t - d] : 0;
        __syncthreads();
        lds[t] += v;
        __syncthreads();
    }
    int excl = lds[t] - tsum;
    if (base + 0 < N) offs[base + 0] = excl;
    if (base + 1 < N) offs[base + 1] = excl + a0;
    if (base + 2 < N) offs[base + 2] = excl + a0 + a1;
    if (base + 3 < N) offs[base + 3] = excl + a0 + a1 + a2;
    if (t == 255) bsums[blockIdx.x] = lds[255];
}

__global__ void k_scan2(int* bsums, int* offs, int nb, int N) {
    if (threadIdx.x == 0 && blockIdx.x == 0) {
        int run = 0;
        for (int i = 0; i < nb; ++i) { int v = bsums[i]; bsums[i] = run; run += v; }
        offs[N] = run;
    }
}

__global__ void k_scan3(int* offs, const int* __restrict__ bsums, int N) {
    int i = blockIdx.x * blockDim.x + threadIdx.x;
    if (i < N) offs[i] += bsums[i >> 10];
}

__global__ void k_scatter(const int* __restrict__ row, const int* __restrict__ col,
                          const float* __restrict__ ew, const float* __restrict__ dinv,
                          const int* __restrict__ offs, int* cursor,
                          int* __restrict__ csr_src, float* __restrict__ csr_w, int E) {
    int e = blockIdx.x * blockDim.x + threadIdx.x;
    if (e < E) {
        int r = row[e], c = col[e];
        float w = dinv[r] * ew[e] * dinv[c];
        int pos = offs[c] + atomicAdd(&cursor[c], 1);
        csr_src[pos] = r;
        csr_w[pos] = w;
    }
}

// Y[n][o] = sum_k X[n][k] * W[o][k]  (h = x @ W.T), fp32 vector ALU.
// 256 thr = 16 og (t>>4, 8 outs each) x 16 ng (t&15, 4 nodes each):
// 64 nodes x 128 outs per block, grid = ceil(N/64). No LDS.
// Per wave: X-load instr touches 16 lines (4 lanes share a row); W-load
// instr touches 4 lines (16 lanes share). X prefetched one k-step ahead.
__global__ __launch_bounds__(256, 4) void k_gemm(const float* __restrict__ X,
                                                 const float* __restrict__ W,
                                                 float* __restrict__ Y, int N) {
    int t = threadIdx.x;
    int og = t >> 4;          // 0..15 -> 8 outs each
    int ng = t & 15;          // 0..15 -> 4 nodes each
    int nbase = blockIdx.x * 64 + ng * 4;
    int ob = og * 8;
    const float* Wb = W + (size_t)ob * 128;

    float acc[4][8];
#pragma unroll
    for (int i = 0; i < 4; ++i)
#pragma unroll
        for (int j = 0; j < 8; ++j) acc[i][j] = 0.f;
    bool v[4];
#pragma unroll
    for (int i = 0; i < 4; ++i) v[i] = (nbase + i) < N;

    float4 xv[4];
#pragma unroll
    for (int i = 0; i < 4; ++i)
        xv[i] = v[i] ? *(const float4*)(X + (size_t)(nbase + i) * 128)
                     : make_float4(0.f, 0.f, 0.f, 0.f);

    for (int k = 0; k < 128; k += 4) {
        float4 wv[8];
#pragma unroll
        for (int j = 0; j < 8; ++j)
            wv[j] = *(const float4*)(Wb + (size_t)j * 128 + k);
        float4 xn[4];
        int kn = k + 4;
        if (kn < 128) {
#pragma unroll
            for (int i = 0; i < 4; ++i)
                xn[i] = v[i] ? *(const float4*)(X + (size_t)(nbase + i) * 128 + kn)
                             : make_float4(0.f, 0.f, 0.f, 0.f);
        }
#pragma unroll
        for (int i = 0; i < 4; ++i)
#pragma unroll
            for (int j = 0; j < 8; ++j)
                acc[i][j] += xv[i].x * wv[j].x + xv[i].y * wv[j].y +
                             xv[i].z * wv[j].z + xv[i].w * wv[j].w;
        if (kn < 128) {
#pragma unroll
            for (int i = 0; i < 4; ++i) xv[i] = xn[i];
        }
    }
#pragma unroll
    for (int i = 0; i < 4; ++i) {
        if (v[i]) {
            float* dst = Y + (size_t)(nbase + i) * 128 + ob;
            *(float4*)dst       = make_float4(acc[i][0], acc[i][1], acc[i][2], acc[i][3]);
            *(float4*)(dst + 4) = make_float4(acc[i][4], acc[i][5], acc[i][6], acc[i][7]);
        }
    }
}

// One wave per node. wid wave-uniform -> offs/csr reads are scalar (s_load);
// edge loop unrolled 8x -> 8 independent 512B row-gathers in flight per wave.
__global__ __launch_bounds__(256) void k_agg(const float* __restrict__ H, float* __restrict__ O,
                                             const int* __restrict__ offs,
                                             const int* __restrict__ csr_src,
                                             const float* __restrict__ csr_w,
                                             const float* __restrict__ dinv,
                                             const float* __restrict__ bias, int N) {
    int wid = __builtin_amdgcn_readfirstlane((blockIdx.x * blockDim.x + threadIdx.x) >> 6);
    int lane = threadIdx.x & 63;
    if (wid >= N) return;
    const float2* H2 = (const float2*)H;
    float di = dinv[wid];
    float sw = di * di;
    float2 h0 = H2[(size_t)wid * 64 + lane];
    float ax = sw * h0.x, ay = sw * h0.y;
    int s = offs[wid], e = offs[wid + 1];
    int j = s;
    for (; j + 8 <= e; j += 8) {
        int   s0 = csr_src[j],   s1 = csr_src[j+1], s2 = csr_src[j+2], s3 = csr_src[j+3];
        int   s4 = csr_src[j+4], s5 = csr_src[j+5], s6 = csr_src[j+6], s7 = csr_src[j+7];
        float w0 = csr_w[j],     w1 = csr_w[j+1],   w2 = csr_w[j+2],   w3 = csr_w[j+3];
        float w4 = csr_w[j+4],   w5 = csr_w[j+5],   w6 = csr_w[j+6],   w7 = csr_w[j+7];
        float2 a0 = H2[(size_t)s0 * 64 + lane];
        float2 a1 = H2[(size_t)s1 * 64 + lane];
        float2 a2 = H2[(size_t)s2 * 64 + lane];
        float2 a3 = H2[(size_t)s3 * 64 + lane];
        float2 a4 = H2[(size_t)s4 * 64 + lane];
        float2 a5 = H2[(size_t)s5 * 64 + lane];
        float2 a6 = H2[(size_t)s6 * 64 + lane];
        float2 a7 = H2[(size_t)s7 * 64 + lane];
        ax += w0 * a0.x; ay += w0 * a0.y;
        ax += w1 * a1.x; ay += w1 * a1.y;
        ax += w2 * a2.x; ay += w2 * a2.y;
        ax += w3 * a3.x; ay += w3 * a3.y;
        ax += w4 * a4.x; ay += w4 * a4.y;
        ax += w5 * a5.x; ay += w5 * a5.y;
        ax += w6 * a6.x; ay += w6 * a6.y;
        ax += w7 * a7.x; ay += w7 * a7.y;
    }
    for (; j < e; ++j) {
        int ss = csr_src[j];
        float ww = csr_w[j];
        float2 hv = H2[(size_t)ss * 64 + lane];
        ax += ww * hv.x; ay += ww * hv.y;
    }
    float2 bb = ((const float2*)bias)[lane];
    ax = fmaxf(ax + bb.x, 0.f);
    ay = fmaxf(ay + bb.y, 0.f);
    ((float2*)O)[(size_t)wid * 64 + lane] = make_float2(ax, ay);
}

// Parallel mean-pool stage 1: each block sums 64 consecutive (batch-sorted)
// nodes per feature column, one atomicAdd per graph segment.
__global__ __launch_bounds__(128) void k_pool(const float* __restrict__ H,
                                              const int* __restrict__ batch,
                                              float* __restrict__ pooled, int N) {
    int t = threadIdx.x;
    int n0 = blockIdx.x * 64;
    if (n0 >= N) return;
    int n1 = min(n0 + 64, N);
    int cur = batch[n0];
    float acc = 0.f;
    for (int n = n0; n < n1; ++n) {
        int g = batch[n];
        if (g != cur) {
            atomicAdd(&pooled[cur * 128 + t], acc);
            acc = 0.f; cur = g;
        }
        acc += H[(size_t)n * 128 + t];
    }
    atomicAdd(&pooled[cur * 128 + t], acc);
}

// Stage 2: divide by count (binary search over sorted batch) + MLP.
__global__ __launch_bounds__(128) void k_mlp(const float* __restrict__ pooled,
                                             const int* __restrict__ batch,
                                             const float* __restrict__ w1,
                                             const float* __restrict__ b1,
                                             const float* __restrict__ w2,
                                             const float* __restrict__ b2,
                                             float* __restrict__ out, int N, int G) {
    __shared__ float pl[128];
    __shared__ float h1[128];
    int g = blockIdx.x, t = threadIdx.x;
    int lo = 0, hi = N;
    while (lo < hi) { int m = (lo + hi) >> 1; if (batch[m] < g) lo = m + 1; else hi = m; }
    int s = lo;
    lo = s; hi = N;
    while (lo < hi) { int m = (lo + hi) >> 1; if (batch[m] < g + 1) lo = m + 1; else hi = m; }
    float cnt = (float)(lo - s);
    pl[t] = pooled[g * 128 + t] / fmaxf(cnt, 1.0f);
    __syncthreads();
    float sum = b1[t];
#pragma unroll 4
    for (int k = 0; k < 128; ++k) sum += w1[t * 128 + k] * pl[k];
    h1[t] = fmaxf(sum, 0.f);
    __syncthreads();
    if (t < 2) {
        float s2 = b2[t];
        for (int k = 0; k < 128; ++k) s2 += w2[t * 128 + k] * h1[k];
        out[g * 2 + t] = s2;
    }
}

extern "C" void kernel_launch(void* const* d_in, const int* in_sizes, int n_in,
                              void* d_out, int out_size, void* d_ws, size_t ws_size,
                              hipStream_t stream) {
    const float* x   = (const float*)d_in[0];
    const int*   ei  = (const int*)d_in[1];
    const float* ew  = (const float*)d_in[2];
    const int* batch = (const int*)d_in[3];
    const float* W1  = (const float*)d_in[4];
    const float* b1  = (const float*)d_in[5];
    const float* W2  = (const float*)d_in[6];
    const float* b2  = (const float*)d_in[7];
    const float* l1w = (const float*)d_in[8];
    const float* l1b = (const float*)d_in[9];
    const float* l2w = (const float*)d_in[10];
    const float* l2b = (const float*)d_in[11];
    float* out = (float*)d_out;

    const int E = in_sizes[2];   // edge_weight count
    const int N = in_sizes[3];   // batch count = nodes
    const int G = out_size / 2;
    const int* row = ei;
    const int* col = ei + E;

    char* p = (char*)d_ws;
    auto alloc = [&](size_t bytes) -> void* {
        void* r = (void*)p;
        p += (bytes + 511) & ~(size_t)511;
        return r;
    };
    float* deg    = (float*)alloc((size_t)N * 4);
    float* dinv   = (float*)alloc((size_t)N * 4);
    int*   counts = (int*)alloc((size_t)N * 4);
    int*   cursor = (int*)alloc((size_t)N * 4);
    int*   offs   = (int*)alloc((size_t)(N + 1) * 4);
    int*   bsums  = (int*)alloc(256 * 4);
    int*   csr_src= (int*)alloc((size_t)E * 4);
    float* csr_w  = (float*)alloc((size_t)E * 4);
    float* hbuf   = (float*)alloc((size_t)N * 128 * 4);
    float* abuf   = (float*)alloc((size_t)N * 128 * 4);
    float* pooled = (float*)alloc((size_t)G * 128 * 4);

    int nbN = (N + 255) / 256;
    int nbE = (E + 255) / 256;
    k_init<<<nbN, 256, 0, stream>>>(deg, counts, cursor, N, pooled, G * 128);
    k_deg_hist<<<nbE, 256, 0, stream>>>(col, ew, deg, counts, E);
    k_dinv<<<nbN, 256, 0, stream>>>(deg, dinv, N);
    int sb = (N + 1023) / 1024;
    k_scan1<<<sb, 256, 0, stream>>>(counts, offs, bsums, N);
    k_scan2<<<1, 64, 0, stream>>>(bsums, offs, sb, N);
    k_scan3<<<nbN, 256, 0, stream>>>(offs, bsums, N);
    k_scatter<<<nbE, 256, 0, stream>>>(row, col, ew, dinv, offs, cursor, csr_src, csr_w, E);

    int gb = (N + 63) / 64;
    int ab = ((size_t)N * 64 + 255) / 256;
    k_gemm<<<gb, 256, 0, stream>>>(x, W1, hbuf, N);
    k_agg<<<ab, 256, 0, stream>>>(hbuf, abuf, offs, csr_src, csr_w, dinv, b1, N);
    k_gemm<<<gb, 256, 0, stream>>>(abuf, W2, hbuf, N);
    k_agg<<<ab, 256, 0, stream>>>(hbuf, abuf, offs, csr_src, csr_w, dinv, b2, N);
    k_pool<<<(N + 63) / 64, 128, 0, stream>>>(abuf, batch, pooled, N);
    k_mlp<<<G, 128, 0, stream>>>(pooled, batch, l1w, l1b, l2w, l2b, out, N, G);
}

// Round 6
// 457.457 us; speedup vs baseline: 1.1899x; 1.1899x over previous
//
#include <hip/hip_runtime.h>

// GCN: 2x GCNConv(128->128) + mean-pool + MLP(128->128->2), fp32.
// R5: k_gemm reverted to R3' (32KB LDS, y-split=2 — best measured, 75us).
// CSR build slimmed: deg+count fused into ONE packed u64 atomic/edge
// (count hi32, ew fixed-point 2^-24 lo32; deg<64 so no carry), dinv fused
// into scan1, CSR entries packed as 8-B (src,w) pairs.

typedef unsigned long long ull;

__global__ void k_init(ull* hist, int* cursor, int N, float* pooled, int M) {
    int i = blockIdx.x * blockDim.x + threadIdx.x;
    if (i < N) { hist[i] = 0ull; cursor[i] = 0; }
    if (i < M) pooled[i] = 0.f;
}

// One packed atomic per edge: hi32 += 1 (count), lo32 += round(ew * 2^24).
__global__ void k_deg_hist(const int* __restrict__ col, const float* __restrict__ ew,
                           ull* hist, int E) {
    int e = blockIdx.x * blockDim.x + threadIdx.x;
    if (e < E) {
        int c = col[e];
        unsigned int q = (unsigned int)rintf(ew[e] * 16777216.0f);
        atomicAdd(&hist[c], (1ull << 32) | (ull)q);
    }
}

// Exclusive scan over counts (hi32 of hist) -> offs[N+1]; also emits
// dinv[i] = rsqrt(1 + lo32*2^-24)  (self-loop weight 1 included).
__global__ void k_scan1(const ull* __restrict__ hist, int* __restrict__ offs,
                        int* __restrict__ bsums, float* __restrict__ dinv, int N) {
    __shared__ int lds[256];
    int t = threadIdx.x;
    int base = blockIdx.x * 1024 + t * 4;
    int a[4];
#pragma unroll
    for (int u = 0; u < 4; ++u) {
        int idx = base + u;
        if (idx < N) {
            ull h = hist[idx];
            a[u] = (int)(h >> 32);
            float deg = 1.0f + (float)(unsigned int)(h & 0xffffffffull) * 5.9604644775390625e-8f;
            dinv[idx] = rsqrtf(deg);
        } else a[u] = 0;
    }
    int tsum = a[0] + a[1] + a[2] + a[3];
    lds[t] = tsum;
    __syncthreads();
    for (int d = 1; d < 256; d <<= 1) {
        int v = (t >= d) ? lds[t - d] : 0;
        __syncthreads();
        lds[t] += v;
        __syncthreads();
    }
    int excl = lds[t] - tsum;
    if (base + 0 < N) offs[base + 0] = excl;
    if (base + 1 < N) offs[base + 1] = excl + a[0];
    if (base + 2 < N) offs[base + 2] = excl + a[0] + a[1];
    if (base + 3 < N) offs[base + 3] = excl + a[0] + a[1] + a[2];
    if (t == 255) bsums[blockIdx.x] = lds[255];
}

__global__ void k_scan2(int* bsums, int* offs, int nb, int N) {
    if (threadIdx.x == 0 && blockIdx.x == 0) {
        int run = 0;
        for (int i = 0; i < nb; ++i) { int v = bsums[i]; bsums[i] = run; run += v; }
        offs[N] = run;
    }
}

__global__ void k_scan3(int* offs, const int* __restrict__ bsums, int N) {
    int i = blockIdx.x * blockDim.x + threadIdx.x;
    if (i < N) offs[i] += bsums[i >> 10];
}

// Scatter edges into dest-sorted CSR as packed (src, w) 8-B pairs.
__global__ void k_scatter(const int* __restrict__ row, const int* __restrict__ col,
                          const float* __restrict__ ew, const float* __restrict__ dinv,
                          const int* __restrict__ offs, int* cursor,
                          ull* __restrict__ epair, int E) {
    int e = blockIdx.x * blockDim.x + threadIdx.x;
    if (e < E) {
        int r = row[e], c = col[e];
        float w = dinv[r] * ew[e] * dinv[c];
        int pos = offs[c] + atomicAdd(&cursor[c], 1);
        epair[pos] = (ull)(unsigned int)r | ((ull)__float_as_uint(w) << 32);
    }
}

// Y[n][o] = sum_k X[n][k] * W[o][k]  (h = x @ W.T), fp32 vector ALU.
// Grid (ceil(N/128), 2): blockIdx.y picks a 64-out half; 64 W rows in 32 KB
// LDS -> 4+ blocks/CU. 256 thr = 8 og (t>>5, 8 outs) x 32 ng (t&31, 4 nodes).
// Wave spans 2 og values -> sW reads 2-way bank-aliased = free (m136).
__global__ __launch_bounds__(256, 4) void k_gemm(const float* __restrict__ X,
                                                 const float* __restrict__ W,
                                                 float* __restrict__ Y, int N) {
    __shared__ float sW[64 * 128];   // 32 KB
    int t = threadIdx.x;
    int obase = blockIdx.y * 64;
    {
        const float4* src = (const float4*)(W + (size_t)obase * 128);
        float4* dst = (float4*)sW;
#pragma unroll
        for (int i = 0; i < 8; ++i)
            dst[t + 256 * i] = src[t + 256 * i];
    }
    __syncthreads();

    int og = t >> 5;          // 0..7  -> 8 outs each (within 64-out half)
    int ng = t & 31;          // 0..31 -> 4 nodes each
    int nbase = blockIdx.x * 128 + ng * 4;
    int ob = og * 8;
    float acc[4][8];
#pragma unroll
    for (int i = 0; i < 4; ++i)
#pragma unroll
        for (int j = 0; j < 8; ++j) acc[i][j] = 0.f;
    bool v[4];
#pragma unroll
    for (int i = 0; i < 4; ++i) v[i] = (nbase + i) < N;

#pragma unroll 2
    for (int k = 0; k < 128; k += 4) {
        float4 xv[4];
#pragma unroll
        for (int i = 0; i < 4; ++i)
            xv[i] = v[i] ? *(const float4*)(X + (size_t)(nbase + i) * 128 + k)
                         : make_float4(0.f, 0.f, 0.f, 0.f);
        float4 wv[8];
#pragma unroll
        for (int j = 0; j < 8; ++j)
            wv[j] = *(const float4*)(sW + (ob + j) * 128 + k);
#pragma unroll
        for (int i = 0; i < 4; ++i)
#pragma unroll
            for (int j = 0; j < 8; ++j)
                acc[i][j] += xv[i].x * wv[j].x + xv[i].y * wv[j].y +
                             xv[i].z * wv[j].z + xv[i].w * wv[j].w;
    }
#pragma unroll
    for (int i = 0; i < 4; ++i) {
        if (v[i]) {
            float* dst = Y + (size_t)(nbase + i) * 128 + obase + ob;
            *(float4*)dst       = make_float4(acc[i][0], acc[i][1], acc[i][2], acc[i][3]);
            *(float4*)(dst + 4) = make_float4(acc[i][4], acc[i][5], acc[i][6], acc[i][7]);
        }
    }
}

// One wave per node. wid wave-uniform -> offs/epair reads are scalar loads;
// edge loop unrolled 8x -> 8 independent 512B row-gathers in flight per wave.
__global__ __launch_bounds__(256) void k_agg(const float* __restrict__ H, float* __restrict__ O,
                                             const int* __restrict__ offs,
                                             const ull* __restrict__ epair,
                                             const float* __restrict__ dinv,
                                             const float* __restrict__ bias, int N) {
    int wid = __builtin_amdgcn_readfirstlane((blockIdx.x * blockDim.x + threadIdx.x) >> 6);
    int lane = threadIdx.x & 63;
    if (wid >= N) return;
    const float2* H2 = (const float2*)H;
    float di = dinv[wid];
    float sw = di * di;
    float2 h0 = H2[(size_t)wid * 64 + lane];
    float ax = sw * h0.x, ay = sw * h0.y;
    int s = offs[wid], e = offs[wid + 1];
    int j = s;
    for (; j + 8 <= e; j += 8) {
        ull p0 = epair[j],   p1 = epair[j+1], p2 = epair[j+2], p3 = epair[j+3];
        ull p4 = epair[j+4], p5 = epair[j+5], p6 = epair[j+6], p7 = epair[j+7];
        int   s0 = (int)(unsigned int)p0, s1 = (int)(unsigned int)p1;
        int   s2 = (int)(unsigned int)p2, s3 = (int)(unsigned int)p3;
        int   s4 = (int)(unsigned int)p4, s5 = (int)(unsigned int)p5;
        int   s6 = (int)(unsigned int)p6, s7 = (int)(unsigned int)p7;
        float w0 = __uint_as_float((unsigned int)(p0 >> 32));
        float w1 = __uint_as_float((unsigned int)(p1 >> 32));
        float w2 = __uint_as_float((unsigned int)(p2 >> 32));
        float w3 = __uint_as_float((unsigned int)(p3 >> 32));
        float w4 = __uint_as_float((unsigned int)(p4 >> 32));
        float w5 = __uint_as_float((unsigned int)(p5 >> 32));
        float w6 = __uint_as_float((unsigned int)(p6 >> 32));
        float w7 = __uint_as_float((unsigned int)(p7 >> 32));
        float2 a0 = H2[(size_t)s0 * 64 + lane];
        float2 a1 = H2[(size_t)s1 * 64 + lane];
        float2 a2 = H2[(size_t)s2 * 64 + lane];
        float2 a3 = H2[(size_t)s3 * 64 + lane];
        float2 a4 = H2[(size_t)s4 * 64 + lane];
        float2 a5 = H2[(size_t)s5 * 64 + lane];
        float2 a6 = H2[(size_t)s6 * 64 + lane];
        float2 a7 = H2[(size_t)s7 * 64 + lane];
        ax += w0 * a0.x; ay += w0 * a0.y;
        ax += w1 * a1.x; ay += w1 * a1.y;
        ax += w2 * a2.x; ay += w2 * a2.y;
        ax += w3 * a3.x; ay += w3 * a3.y;
        ax += w4 * a4.x; ay += w4 * a4.y;
        ax += w5 * a5.x; ay += w5 * a5.y;
        ax += w6 * a6.x; ay += w6 * a6.y;
        ax += w7 * a7.x; ay += w7 * a7.y;
    }
    for (; j < e; ++j) {
        ull pp = epair[j];
        int ss = (int)(unsigned int)pp;
        float ww = __uint_as_float((unsigned int)(pp >> 32));
        float2 hv = H2[(size_t)ss * 64 + lane];
        ax += ww * hv.x; ay += ww * hv.y;
    }
    float2 bb = ((const float2*)bias)[lane];
    ax = fmaxf(ax + bb.x, 0.f);
    ay = fmaxf(ay + bb.y, 0.f);
    ((float2*)O)[(size_t)wid * 64 + lane] = make_float2(ax, ay);
}

// Parallel mean-pool stage 1: each block sums 64 consecutive (batch-sorted)
// nodes per feature column, one atomicAdd per graph segment.
__global__ __launch_bounds__(128) void k_pool(const float* __restrict__ H,
                                              const int* __restrict__ batch,
                                              float* __restrict__ pooled, int N) {
    int t = threadIdx.x;
    int n0 = blockIdx.x * 64;
    if (n0 >= N) return;
    int n1 = min(n0 + 64, N);
    int cur = batch[n0];
    float acc = 0.f;
    for (int n = n0; n < n1; ++n) {
        int g = batch[n];
        if (g != cur) {
            atomicAdd(&pooled[cur * 128 + t], acc);
            acc = 0.f; cur = g;
        }
        acc += H[(size_t)n * 128 + t];
    }
    atomicAdd(&pooled[cur * 128 + t], acc);
}

// Stage 2: divide by count (binary search over sorted batch) + MLP.
__global__ __launch_bounds__(128) void k_mlp(const float* __restrict__ pooled,
                                             const int* __restrict__ batch,
                                             const float* __restrict__ w1,
                                             const float* __restrict__ b1,
                                             const float* __restrict__ w2,
                                             const float* __restrict__ b2,
                                             float* __restrict__ out, int N, int G) {
    __shared__ float pl[128];
    __shared__ float h1[128];
    int g = blockIdx.x, t = threadIdx.x;
    int lo = 0, hi = N;
    while (lo < hi) { int m = (lo + hi) >> 1; if (batch[m] < g) lo = m + 1; else hi = m; }
    int s = lo;
    lo = s; hi = N;
    while (lo < hi) { int m = (lo + hi) >> 1; if (batch[m] < g + 1) lo = m + 1; else hi = m; }
    float cnt = (float)(lo - s);
    pl[t] = pooled[g * 128 + t] / fmaxf(cnt, 1.0f);
    __syncthreads();
    float sum = b1[t];
#pragma unroll 4
    for (int k = 0; k < 128; ++k) sum += w1[t * 128 + k] * pl[k];
    h1[t] = fmaxf(sum, 0.f);
    __syncthreads();
    if (t < 2) {
        float s2 = b2[t];
        for (int k = 0; k < 128; ++k) s2 += w2[t * 128 + k] * h1[k];
        out[g * 2 + t] = s2;
    }
}

extern "C" void kernel_launch(void* const* d_in, const int* in_sizes, int n_in,
                              void* d_out, int out_size, void* d_ws, size_t ws_size,
                              hipStream_t stream) {
    const float* x   = (const float*)d_in[0];
    const int*   ei  = (const int*)d_in[1];
    const float* ew  = (const float*)d_in[2];
    const int* batch = (const int*)d_in[3];
    const float* W1  = (const float*)d_in[4];
    const float* b1  = (const float*)d_in[5];
    const float* W2  = (const float*)d_in[6];
    const float* b2  = (const float*)d_in[7];
    const float* l1w = (const float*)d_in[8];
    const float* l1b = (const float*)d_in[9];
    const float* l2w = (const float*)d_in[10];
    const float* l2b = (const float*)d_in[11];
    float* out = (float*)d_out;

    const int E = in_sizes[2];   // edge_weight count
    const int N = in_sizes[3];   // batch count = nodes
    const int G = out_size / 2;
    const int* row = ei;
    const int* col = ei + E;

    char* p = (char*)d_ws;
    auto alloc = [&](size_t bytes) -> void* {
        void* r = (void*)p;
        p += (bytes + 511) & ~(size_t)511;
        return r;
    };
    ull*   hist   = (ull*)alloc((size_t)N * 8);
    float* dinv   = (float*)alloc((size_t)N * 4);
    int*   cursor = (int*)alloc((size_t)N * 4);
    int*   offs   = (int*)alloc((size_t)(N + 1) * 4);
    int*   bsums  = (int*)alloc(256 * 4);
    ull*   epair  = (ull*)alloc((size_t)E * 8);
    float* hbuf   = (float*)alloc((size_t)N * 128 * 4);
    float* abuf   = (float*)alloc((size_t)N * 128 * 4);
    float* pooled = (float*)alloc((size_t)G * 128 * 4);

    int nbN = (N + 255) / 256;
    int nbE = (E + 255) / 256;
    k_init<<<nbN, 256, 0, stream>>>(hist, cursor, N, pooled, G * 128);
    k_deg_hist<<<nbE, 256, 0, stream>>>(col, ew, hist, E);
    int sb = (N + 1023) / 1024;
    k_scan1<<<sb, 256, 0, stream>>>(hist, offs, bsums, dinv, N);
    k_scan2<<<1, 64, 0, stream>>>(bsums, offs, sb, N);
    k_scan3<<<nbN, 256, 0, stream>>>(offs, bsums, N);
    k_scatter<<<nbE, 256, 0, stream>>>(row, col, ew, dinv, offs, cursor, epair, E);

    dim3 gg((N + 127) / 128, 2);
    int ab = ((size_t)N * 64 + 255) / 256;
    k_gemm<<<gg, 256, 0, stream>>>(x, W1, hbuf, N);
    k_agg<<<ab, 256, 0, stream>>>(hbuf, abuf, offs, epair, dinv, b1, N);
    k_gemm<<<gg, 256, 0, stream>>>(abuf, W2, hbuf, N);
    k_agg<<<ab, 256, 0, stream>>>(hbuf, abuf, offs, epair, dinv, b2, N);
    k_pool<<<(N + 63) / 64, 128, 0, stream>>>(abuf, batch, pooled, N);
    k_mlp<<<G, 128, 0, stream>>>(pooled, batch, l1w, l1b, l2w, l2b, out, N, G);
}

// Round 7
// 358.862 us; speedup vs baseline: 1.5168x; 1.2747x over previous
//
#include <hip/hip_runtime.h>

// GCN: 2x GCNConv(128->128) + mean-pool + MLP(128->128->2), fp32.
// R6: GEMMs moved to MFMA via split-fp32 (x = hi_bf16 + lo_bf16, 3 MFMA
// passes: hihi+hilo+lohi, fp32 accum, ~2^-15 rel err). W staged in LDS as
// bf16 hi/lo, stride 136 (16B-aligned rows, bank-balanced). k_agg templated:
// layer1 emits bf16 hi/lo pairs (gemm2 input), layer2 emits fp32 (pool).

typedef unsigned long long ull;
typedef short bf16x8 __attribute__((ext_vector_type(8)));
typedef float f32x4 __attribute__((ext_vector_type(4)));

__device__ inline ushort f2bf(float f) {
    unsigned u = __float_as_uint(f);
    unsigned r = (u + 0x7FFF + ((u >> 16) & 1)) >> 16;
    return (ushort)r;
}
__device__ inline void bsplit(float f, ushort& h, ushort& l) {
    h = f2bf(f);
    float hf = __uint_as_float(((unsigned)h) << 16);
    l = f2bf(f - hf);
}

__global__ void k_init(ull* hist, int* cursor, int N, float* pooled, int M) {
    int i = blockIdx.x * blockDim.x + threadIdx.x;
    if (i < N) { hist[i] = 0ull; cursor[i] = 0; }
    if (i < M) pooled[i] = 0.f;
}

// Split fp32 -> (hi,lo) bf16 arrays, float4-granular.
__global__ void k_conv(const float* __restrict__ X, ushort* __restrict__ Hhi,
                       ushort* __restrict__ Hlo, int total4) {
    int i = blockIdx.x * blockDim.x + threadIdx.x;
    if (i < total4) {
        float4 v = ((const float4*)X)[i];
        ushort4 h, l;
        bsplit(v.x, h.x, l.x);
        bsplit(v.y, h.y, l.y);
        bsplit(v.z, h.z, l.z);
        bsplit(v.w, h.w, l.w);
        ((ushort4*)Hhi)[i] = h;
        ((ushort4*)Hlo)[i] = l;
    }
}

// One packed atomic per edge: hi32 += 1 (count), lo32 += round(ew * 2^24).
__global__ void k_deg_hist(const int* __restrict__ col, const float* __restrict__ ew,
                           ull* hist, int E) {
    int e = blockIdx.x * blockDim.x + threadIdx.x;
    if (e < E) {
        int c = col[e];
        unsigned int q = (unsigned int)rintf(ew[e] * 16777216.0f);
        atomicAdd(&hist[c], (1ull << 32) | (ull)q);
    }
}

// Exclusive scan over counts (hi32 of hist) -> offs[N+1]; also emits
// dinv[i] = rsqrt(1 + lo32*2^-24)  (self-loop weight 1 included).
__global__ void k_scan1(const ull* __restrict__ hist, int* __restrict__ offs,
                        int* __restrict__ bsums, float* __restrict__ dinv, int N) {
    __shared__ int lds[256];
    int t = threadIdx.x;
    int base = blockIdx.x * 1024 + t * 4;
    int a[4];
#pragma unroll
    for (int u = 0; u < 4; ++u) {
        int idx = base + u;
        if (idx < N) {
            ull h = hist[idx];
            a[u] = (int)(h >> 32);
            float deg = 1.0f + (float)(unsigned int)(h & 0xffffffffull) * 5.9604644775390625e-8f;
            dinv[idx] = rsqrtf(deg);
        } else a[u] = 0;
    }
    int tsum = a[0] + a[1] + a[2] + a[3];
    lds[t] = tsum;
    __syncthreads();
    for (int d = 1; d < 256; d <<= 1) {
        int v = (t >= d) ? lds[t - d] : 0;
        __syncthreads();
        lds[t] += v;
        __syncthreads();
    }
    int excl = lds[t] - tsum;
    if (base + 0 < N) offs[base + 0] = excl;
    if (base + 1 < N) offs[base + 1] = excl + a[0];
    if (base + 2 < N) offs[base + 2] = excl + a[0] + a[1];
    if (base + 3 < N) offs[base + 3] = excl + a[0] + a[1] + a[2];
    if (t == 255) bsums[blockIdx.x] = lds[255];
}

__global__ void k_scan2(int* bsums, int* offs, int nb, int N) {
    if (threadIdx.x == 0 && blockIdx.x == 0) {
        int run = 0;
        for (int i = 0; i < nb; ++i) { int v = bsums[i]; bsums[i] = run; run += v; }
        offs[N] = run;
    }
}

__global__ void k_scan3(int* offs, const int* __restrict__ bsums, int N) {
    int i = blockIdx.x * blockDim.x + threadIdx.x;
    if (i < N) offs[i] += bsums[i >> 10];
}

// Scatter edges into dest-sorted CSR as packed (src, w) 8-B pairs.
__global__ void k_scatter(const int* __restrict__ row, const int* __restrict__ col,
                          const float* __restrict__ ew, const float* __restrict__ dinv,
                          const int* __restrict__ offs, int* cursor,
                          ull* __restrict__ epair, int E) {
    int e = blockIdx.x * blockDim.x + threadIdx.x;
    if (e < E) {
        int r = row[e], c = col[e];
        float w = dinv[r] * ew[e] * dinv[c];
        int pos = offs[c] + atomicAdd(&cursor[c], 1);
        epair[pos] = (ull)(unsigned int)r | ((ull)__float_as_uint(w) << 32);
    }
}

// Y[n][o] = sum_k X[n][k]*W[o][k] via split-bf16 MFMA (16x16x32).
// Block: 256 thr = 4 waves, 128 rows x 128 cols. Wave: 2 row-tiles x 8
// col-tiles, acc 64 VGPR. W staged in LDS as bf16 hi/lo, row stride 136
// (272 B: 16B-aligned, 8-beat bank-balanced for ds_read_b128).
// Fragment layouts (verified, docs §3): A[m=lane&15][k=quad*8+j],
// B[k=quad*8+j][n=lane&15], D col=lane&15 row=quad*4+reg.
__global__ __launch_bounds__(256, 2) void k_gemm(const ushort* __restrict__ Xhi,
                                                 const ushort* __restrict__ Xlo,
                                                 const float* __restrict__ W,
                                                 float* __restrict__ Y, int N) {
    __shared__ ushort sWhi[128 * 136];
    __shared__ ushort sWlo[128 * 136];
    int t = threadIdx.x;
#pragma unroll
    for (int i = 0; i < 16; ++i) {
        int idx = i * 256 + t;          // float4 index, 4096 total
        int r = idx >> 5;               // row 0..127
        int c = (idx & 31) << 2;        // col 0,4,...,124
        float4 v = ((const float4*)W)[idx];
        int base = r * 136 + c;
        ushort h, l;
        bsplit(v.x, h, l); sWhi[base + 0] = h; sWlo[base + 0] = l;
        bsplit(v.y, h, l); sWhi[base + 1] = h; sWlo[base + 1] = l;
        bsplit(v.z, h, l); sWhi[base + 2] = h; sWlo[base + 2] = l;
        bsplit(v.w, h, l); sWhi[base + 3] = h; sWlo[base + 3] = l;
    }
    __syncthreads();

    int lane = t & 63;
    int wave = t >> 6;
    int quad = lane >> 4;
    int l16  = lane & 15;
    int rowbase = blockIdx.x * 128 + wave * 32;

    const f32x4 zero = {0.f, 0.f, 0.f, 0.f};
    f32x4 acc[2][8];
#pragma unroll
    for (int i = 0; i < 2; ++i)
#pragma unroll
        for (int j = 0; j < 8; ++j) acc[i][j] = zero;

#pragma unroll
    for (int kc = 0; kc < 128; kc += 32) {
        bf16x8 ah[2], al[2];
#pragma unroll
        for (int rt = 0; rt < 2; ++rt) {
            size_t off = (size_t)(rowbase + rt * 16 + l16) * 128 + kc + quad * 8;
            ah[rt] = *(const bf16x8*)(Xhi + off);
            al[rt] = *(const bf16x8*)(Xlo + off);
        }
#pragma unroll
        for (int ct = 0; ct < 8; ++ct) {
            int boff = (ct * 16 + l16) * 136 + kc + quad * 8;
            bf16x8 bh = *(const bf16x8*)(sWhi + boff);
            bf16x8 bl = *(const bf16x8*)(sWlo + boff);
#pragma unroll
            for (int rt = 0; rt < 2; ++rt) {
                acc[rt][ct] = __builtin_amdgcn_mfma_f32_16x16x32_bf16(ah[rt], bh, acc[rt][ct], 0, 0, 0);
                acc[rt][ct] = __builtin_amdgcn_mfma_f32_16x16x32_bf16(ah[rt], bl, acc[rt][ct], 0, 0, 0);
                acc[rt][ct] = __builtin_amdgcn_mfma_f32_16x16x32_bf16(al[rt], bh, acc[rt][ct], 0, 0, 0);
            }
        }
    }
#pragma unroll
    for (int rt = 0; rt < 2; ++rt) {
#pragma unroll
        for (int r = 0; r < 4; ++r) {
            int rowi = rowbase + rt * 16 + quad * 4 + r;
            if (rowi < N) {
                float* yp = Y + (size_t)rowi * 128 + l16;
#pragma unroll
                for (int ct = 0; ct < 8; ++ct)
                    yp[ct * 16] = acc[rt][ct][r];
            }
        }
    }
}

// One wave per node; scalar CSR loads, 8x-unrolled gathers. PAIR=1: emit
// bf16 hi/lo pair arrays (next gemm's input); PAIR=0: emit fp32.
template <int PAIR>
__global__ __launch_bounds__(256) void k_agg_t(const float* __restrict__ H,
                                               float* __restrict__ O,
                                               ushort* __restrict__ Ohi,
                                               ushort* __restrict__ Olo,
                                               const int* __restrict__ offs,
                                               const ull* __restrict__ epair,
                                               const float* __restrict__ dinv,
                                               const float* __restrict__ bias, int N) {
    int wid = __builtin_amdgcn_readfirstlane((blockIdx.x * blockDim.x + threadIdx.x) >> 6);
    int lane = threadIdx.x & 63;
    if (wid >= N) return;
    const float2* H2 = (const float2*)H;
    float di = dinv[wid];
    float sw = di * di;
    float2 h0 = H2[(size_t)wid * 64 + lane];
    float ax = sw * h0.x, ay = sw * h0.y;
    int s = offs[wid], e = offs[wid + 1];
    int j = s;
    for (; j + 8 <= e; j += 8) {
        ull p0 = epair[j],   p1 = epair[j+1], p2 = epair[j+2], p3 = epair[j+3];
        ull p4 = epair[j+4], p5 = epair[j+5], p6 = epair[j+6], p7 = epair[j+7];
        int   s0 = (int)(unsigned int)p0, s1 = (int)(unsigned int)p1;
        int   s2 = (int)(unsigned int)p2, s3 = (int)(unsigned int)p3;
        int   s4 = (int)(unsigned int)p4, s5 = (int)(unsigned int)p5;
        int   s6 = (int)(unsigned int)p6, s7 = (int)(unsigned int)p7;
        float w0 = __uint_as_float((unsigned int)(p0 >> 32));
        float w1 = __uint_as_float((unsigned int)(p1 >> 32));
        float w2 = __uint_as_float((unsigned int)(p2 >> 32));
        float w3 = __uint_as_float((unsigned int)(p3 >> 32));
        float w4 = __uint_as_float((unsigned int)(p4 >> 32));
        float w5 = __uint_as_float((unsigned int)(p5 >> 32));
        float w6 = __uint_as_float((unsigned int)(p6 >> 32));
        float w7 = __uint_as_float((unsigned int)(p7 >> 32));
        float2 a0 = H2[(size_t)s0 * 64 + lane];
        float2 a1 = H2[(size_t)s1 * 64 + lane];
        float2 a2 = H2[(size_t)s2 * 64 + lane];
        float2 a3 = H2[(size_t)s3 * 64 + lane];
        float2 a4 = H2[(size_t)s4 * 64 + lane];
        float2 a5 = H2[(size_t)s5 * 64 + lane];
        float2 a6 = H2[(size_t)s6 * 64 + lane];
        float2 a7 = H2[(size_t)s7 * 64 + lane];
        ax += w0 * a0.x; ay += w0 * a0.y;
        ax += w1 * a1.x; ay += w1 * a1.y;
        ax += w2 * a2.x; ay += w2 * a2.y;
        ax += w3 * a3.x; ay += w3 * a3.y;
        ax += w4 * a4.x; ay += w4 * a4.y;
        ax += w5 * a5.x; ay += w5 * a5.y;
        ax += w6 * a6.x; ay += w6 * a6.y;
        ax += w7 * a7.x; ay += w7 * a7.y;
    }
    for (; j < e; ++j) {
        ull pp = epair[j];
        int ss = (int)(unsigned int)pp;
        float ww = __uint_as_float((unsigned int)(pp >> 32));
        float2 hv = H2[(size_t)ss * 64 + lane];
        ax += ww * hv.x; ay += ww * hv.y;
    }
    float2 bb = ((const float2*)bias)[lane];
    ax = fmaxf(ax + bb.x, 0.f);
    ay = fmaxf(ay + bb.y, 0.f);
    if (PAIR) {
        ushort hx, lx, hy, ly;
        bsplit(ax, hx, lx);
        bsplit(ay, hy, ly);
        ushort2 hv2; hv2.x = hx; hv2.y = hy;
        ushort2 lv2; lv2.x = lx; lv2.y = ly;
        ((ushort2*)Ohi)[(size_t)wid * 64 + lane] = hv2;
        ((ushort2*)Olo)[(size_t)wid * 64 + lane] = lv2;
    } else {
        ((float2*)O)[(size_t)wid * 64 + lane] = make_float2(ax, ay);
    }
}

// Parallel mean-pool stage 1.
__global__ __launch_bounds__(128) void k_pool(const float* __restrict__ H,
                                              const int* __restrict__ batch,
                                              float* __restrict__ pooled, int N) {
    int t = threadIdx.x;
    int n0 = blockIdx.x * 64;
    if (n0 >= N) return;
    int n1 = min(n0 + 64, N);
    int cur = batch[n0];
    float acc = 0.f;
    for (int n = n0; n < n1; ++n) {
        int g = batch[n];
        if (g != cur) {
            atomicAdd(&pooled[cur * 128 + t], acc);
            acc = 0.f; cur = g;
        }
        acc += H[(size_t)n * 128 + t];
    }
    atomicAdd(&pooled[cur * 128 + t], acc);
}

// Stage 2: divide by count (binary search over sorted batch) + MLP.
__global__ __launch_bounds__(128) void k_mlp(const float* __restrict__ pooled,
                                             const int* __restrict__ batch,
                                             const float* __restrict__ w1,
                                             const float* __restrict__ b1,
                                             const float* __restrict__ w2,
                                             const float* __restrict__ b2,
                                             float* __restrict__ out, int N, int G) {
    __shared__ float pl[128];
    __shared__ float h1[128];
    int g = blockIdx.x, t = threadIdx.x;
    int lo = 0, hi = N;
    while (lo < hi) { int m = (lo + hi) >> 1; if (batch[m] < g) lo = m + 1; else hi = m; }
    int s = lo;
    lo = s; hi = N;
    while (lo < hi) { int m = (lo + hi) >> 1; if (batch[m] < g + 1) lo = m + 1; else hi = m; }
    float cnt = (float)(lo - s);
    pl[t] = pooled[g * 128 + t] / fmaxf(cnt, 1.0f);
    __syncthreads();
    float sum = b1[t];
#pragma unroll 4
    for (int k = 0; k < 128; ++k) sum += w1[t * 128 + k] * pl[k];
    h1[t] = fmaxf(sum, 0.f);
    __syncthreads();
    if (t < 2) {
        float s2 = b2[t];
        for (int k = 0; k < 128; ++k) s2 += w2[t * 128 + k] * h1[k];
        out[g * 2 + t] = s2;
    }
}

extern "C" void kernel_launch(void* const* d_in, const int* in_sizes, int n_in,
                              void* d_out, int out_size, void* d_ws, size_t ws_size,
                              hipStream_t stream) {
    const float* x   = (const float*)d_in[0];
    const int*   ei  = (const int*)d_in[1];
    const float* ew  = (const float*)d_in[2];
    const int* batch = (const int*)d_in[3];
    const float* W1  = (const float*)d_in[4];
    const float* b1  = (const float*)d_in[5];
    const float* W2  = (const float*)d_in[6];
    const float* b2  = (const float*)d_in[7];
    const float* l1w = (const float*)d_in[8];
    const float* l1b = (const float*)d_in[9];
    const float* l2w = (const float*)d_in[10];
    const float* l2b = (const float*)d_in[11];
    float* out = (float*)d_out;

    const int E = in_sizes[2];   // edge_weight count
    const int N = in_sizes[3];   // batch count = nodes
    const int G = out_size / 2;
    const int Npad = (N + 127) & ~127;
    const int* row = ei;
    const int* col = ei + E;

    char* p = (char*)d_ws;
    auto alloc = [&](size_t bytes) -> void* {
        void* r = (void*)p;
        p += (bytes + 511) & ~(size_t)511;
        return r;
    };
    ull*   hist   = (ull*)alloc((size_t)N * 8);
    float* dinv   = (float*)alloc((size_t)N * 4);
    int*   cursor = (int*)alloc((size_t)N * 4);
    int*   offs   = (int*)alloc((size_t)(N + 1) * 4);
    int*   bsums  = (int*)alloc(256 * 4);
    ull*   epair  = (ull*)alloc((size_t)E * 8);
    ushort* phi   = (ushort*)alloc((size_t)Npad * 128 * 2);  // bf16 hi
    ushort* plo   = (ushort*)alloc((size_t)Npad * 128 * 2);  // bf16 lo
    float* hbuf   = (float*)alloc((size_t)Npad * 128 * 4);
    float* pooled = (float*)alloc((size_t)G * 128 * 4);
    float* abuf   = (float*)phi;  // alias: phi/plo dead after gemm2 (25.7 MB >= 25.6)

    int nbN = (N + 255) / 256;
    int nbE = (E + 255) / 256;
    k_init<<<nbN, 256, 0, stream>>>(hist, cursor, N, pooled, G * 128);
    int cv = (N * 32 + 255) / 256;
    k_conv<<<cv, 256, 0, stream>>>(x, phi, plo, N * 32);
    k_deg_hist<<<nbE, 256, 0, stream>>>(col, ew, hist, E);
    int sb = (N + 1023) / 1024;
    k_scan1<<<sb, 256, 0, stream>>>(hist, offs, bsums, dinv, N);
    k_scan2<<<1, 64, 0, stream>>>(bsums, offs, sb, N);
    k_scan3<<<nbN, 256, 0, stream>>>(offs, bsums, N);
    k_scatter<<<nbE, 256, 0, stream>>>(row, col, ew, dinv, offs, cursor, epair, E);

    int gb = Npad / 128;
    int ab = ((size_t)N * 64 + 255) / 256;
    k_gemm<<<gb, 256, 0, stream>>>(phi, plo, W1, hbuf, N);
    k_agg_t<1><<<ab, 256, 0, stream>>>(hbuf, nullptr, phi, plo, offs, epair, dinv, b1, N);
    k_gemm<<<gb, 256, 0, stream>>>(phi, plo, W2, hbuf, N);
    k_agg_t<0><<<ab, 256, 0, stream>>>(hbuf, abuf, nullptr, nullptr, offs, epair, dinv, b2, N);
    k_pool<<<(N + 63) / 64, 128, 0, stream>>>(abuf, batch, pooled, N);
    k_mlp<<<G, 128, 0, stream>>>(pooled, batch, l1w, l1b, l2w, l2b, out, N, G);
}